// Round 14
// baseline (256.650 us; speedup 1.0000x reference)
//
#include <hip/hip_runtime.h>

#define BB 128
#define SS 64
#define KK 10
#define DD 256
#define NN (BB*SS)        // 8192 rows
#define ROWS 16           // rows per block
#define NBLK (NN/ROWS)    // 512 blocks = 2 per CU: cross-block TLP fills barrier stalls
#define NT 512            // 8 waves; wave owns column groups w and w+8

typedef __attribute__((ext_vector_type(8))) short short8;
typedef __attribute__((ext_vector_type(4))) float f32x4;
typedef __attribute__((ext_vector_type(4))) unsigned uint4v;

#define FRAG_ELEMS (48*8*64*8)   // 196608 bf16 values per weight matrix
#define FRAG_ROWS  (48*8*64)     // 24576 8-element fragment rows per matrix

__device__ __forceinline__ unsigned short f2bf(float f){
  union { float f; unsigned u; } v; v.f = f;
  unsigned r = (v.u + 0x7FFFu + ((v.u >> 16) & 1u)) >> 16;
  return (unsigned short)r;
}

// packed RNE f32->bf16 pair (no builtin on gfx950); same rounding as f2bf.
__device__ __forceinline__ unsigned cvtpk(float lo, float hi){
  unsigned r;
  asm("v_cvt_pk_bf16_f32 %0, %1, %2" : "=v"(r) : "v"(lo), "v"(hi));
  return r;
}

// Pre-swizzle W_ih[:, :D] and W_hh into bf16 MFMA B-fragment order (r13
// vectorized form, proven): one thread per 8-contiguous fragment row.
__global__ void prep_weights(const float* __restrict__ Wih,
                             const float* __restrict__ Whh,
                             unsigned short* __restrict__ fw){
  int t = blockIdx.x * 256 + threadIdx.x;      // 0 .. 2*FRAG_ROWS-1
  int arr = (t >= FRAG_ROWS);
  int r = arr ? (t - FRAG_ROWS) : t;
  int l  = r & 63;
  int tk = (r >> 6) & 7;
  int tn = r >> 9;                             // 0..47
  int c  = tn * 16 + (l & 15);                 // 0..767
  int d0 = tk * 32 + ((l >> 4) << 3);          // 0..255, 8-aligned
  const float* src = arr ? (Whh + (size_t)c*256 + d0) : (Wih + (size_t)c*512 + d0);
  const float4* p = (const float4*)src;
  float4 a0 = p[0], a1 = p[1];
  unsigned short o[8];
  o[0]=f2bf(a0.x); o[1]=f2bf(a0.y); o[2]=f2bf(a0.z); o[3]=f2bf(a0.w);
  o[4]=f2bf(a1.x); o[5]=f2bf(a1.y); o[6]=f2bf(a1.z); o[7]=f2bf(a1.w);
  *(short8*)&fw[(size_t)t*8] = *(short8*)o;
}

// 2-BLOCKS-PER-CU GEOMETRY (m114 mechanism: independent co-resident blocks'
// waves overlap fully -- block B computes while block A sits at its barrier).
// Per-wave work is IDENTICAL to the proven r9/r12 kernel (115us): the 2-row-
// tile (mt) dimension is traded for a 2-column-group dimension (wave owns
// channels d and d+128). Same MFMA count, same gi/acc/h register footprint,
// same barrier count, same liveness governors (tk-skew, sched_barrier(0),
// capped unrolls -- r11: removing them spills). launch_bounds(512,4) = 4
// waves/SIMD residency = 2 blocks/CU, 128-reg/wave budget (same as r12).
// LDS 35 KB/block -> 70 KB/CU. Spill signature: WRITE >> 3 MB.
__global__ __launch_bounds__(NT, 4) void gru_main(
    const float* __restrict__ item, const float* __restrict__ user,
    const float* __restrict__ b_ih, const float* __restrict__ b_hh,
    const float* __restrict__ w_out, const float* __restrict__ b_out,
    const int* __restrict__ length, const unsigned short* __restrict__ ws,
    float* __restrict__ out)
{
  // A-fragment layout: elem (tk, lane, j) at ((tk)*64+lane)*8+j  (one 16-row tile)
  // xfrag[s] holds x for step 2c+s of the current chunk.
  __shared__ unsigned short xfrag[2][8*64*8];   // 8 KB x2
  __shared__ unsigned short hfrag[2][8*64*8];   // 8 KB x2
  __shared__ float yp[3][16][4][4];             // 3 KB, triple-buffered

  const int tid  = threadIdx.x;
  const int lane = tid & 63;
  const int w    = tid >> 6;        // wave 0..7; owns column groups w and w+8
  const int col  = lane & 15;       // C-layout col
  const int q    = lane >> 4;       // quad
  const int nb   = blockIdx.x * ROWS;
  const int b    = nb / SS;         // 4 blocks per user
  const int sk   = blockIdx.x & 7;  // tk read-order skew + liveness governor

  const short8* fw1 = (const short8*)ws;
  const short8* fwh = fw1 + (FRAG_ELEMS/8);

  // the 2 owned channels: d0 = w*16+col (0..127), d1 = d0+128
  const int d0 = w*16 + col;
  const int d1 = d0 + 128;
  float br_g[2], bz_g[2], bin_g[2], bhn_g[2], wo_g[2];
  br_g[0]  = b_ih[d0]       + b_hh[d0];       br_g[1]  = b_ih[d1]       + b_hh[d1];
  bz_g[0]  = b_ih[256 + d0] + b_hh[256 + d0]; bz_g[1]  = b_ih[256 + d1] + b_hh[256 + d1];
  bin_g[0] = b_ih[512 + d0];                  bin_g[1] = b_ih[512 + d1];
  bhn_g[0] = b_hh[512 + d0];                  bhn_g[1] = b_hh[512 + d1];
  wo_g[0]  = w_out[d0];                       wo_g[1]  = w_out[d1];

  // weight fragment flat offsets (short8 units): frag(tn,tk) = fw[tn*512 + tk*64 + lane]
  // group 0 (=w) at wq*; group 1 (=w+8) at +8*512 = +4096.
  const int wq0 = (w     )*512 + lane;   // gate r
  const int wq1 = (16 + w)*512 + lane;   // gate z
  const int wq2 = (32 + w)*512 + lane;   // gate n

  // h0 = user_embs[b, clip(length[b]-1,0)]; identical for all rows
  int idx = length[b] - 1; if (idx < 0) idx = 0;
  float u0g[2];
  u0g[0] = user[((size_t)b*SS + idx)*DD + d0];
  u0g[1] = user[((size_t)b*SS + idx)*DD + d1];
  float h[2][4];                    // [g][reg]
  #pragma unroll
  for (int g = 0; g < 2; ++g)
    #pragma unroll
    for (int reg = 0; reg < 4; ++reg)
      h[g][reg] = u0g[g];

  // owner-thread scatter indices: d1's tk-block = tkk+4; slb/dj shared
  const int tkk = d0 >> 5;          // 0..3
  const int slb = ((d0 >> 3) & 3) * 16;
  const int dj  = d0 & 7;
  #pragma unroll
  for (int g = 0; g < 2; ++g){
    unsigned short hb = f2bf(u0g[g]);
    #pragma unroll
    for (int reg = 0; reg < 4; ++reg)
      hfrag[0][((tkk + 4*g)*64 + slb + q*4 + reg)*8 + dj] = hb;
  }

  // cooperative x staging for steps 0 and 1: thread covers row=tid>>5 (0..15),
  // 8 d's at (tid&31)*8
  const int xrow = tid >> 5;        // 0..15
  const int xo   = tid & 31;        // which 8-wide d chunk
  const int xtk  = xo >> 2;
  const int xsl  = (xo & 3)*16 + xrow;
  #pragma unroll
  for (int s = 0; s < 2; ++s){
    const float4* p = (const float4*)(item + ((size_t)(nb + xrow)*KK + s)*DD + xo*8);
    float4 a0 = p[0], a1 = p[1];
    uint4v t;
    t.x = cvtpk(a0.x, a0.y); t.y = cvtpk(a0.z, a0.w);
    t.z = cvtpk(a1.x, a1.y); t.w = cvtpk(a1.z, a1.w);
    *(uint4v*)&xfrag[s][((xtk)*64 + xsl)*8] = t;
  }
  __syncthreads();

  const float bout = b_out[0];

#define MFMA16(A,Bv,C) __builtin_amdgcn_mfma_f32_16x16x32_bf16(A,Bv,C,0,0,0)

  for (int c = 0; c < KK/2; ++c){
    // ---------- GI GEMM: x-part of gates for steps 2c and 2c+1 ----------
    f32x4 gi[2][2][3];   // [step][g][r,z,n]
    #pragma unroll
    for (int s = 0; s < 2; ++s)
      #pragma unroll
      for (int g = 0; g < 2; ++g)
        #pragma unroll
        for (int kd = 0; kd < 3; ++kd){
          f32x4 z4 = {0.f, 0.f, 0.f, 0.f};
          gi[s][g][kd] = z4;
        }

    #pragma unroll 2
    for (int tk = 0; tk < 8; ++tk){
      const int tkv = (tk + sk) & 7;
      const int o_  = tkv * 64;
      short8 wr0 = fw1[wq0+o_],      wz0 = fw1[wq1+o_],      wn0 = fw1[wq2+o_];
      short8 wr1 = fw1[wq0+4096+o_], wz1 = fw1[wq1+4096+o_], wn1 = fw1[wq2+4096+o_];
      short8 a0 = *(const short8*)&xfrag[0][((tkv)*64 + lane)*8];
      short8 a1 = *(const short8*)&xfrag[1][((tkv)*64 + lane)*8];
      __builtin_amdgcn_s_setprio(1);
      gi[0][0][0] = MFMA16(a0, wr0, gi[0][0][0]);
      gi[0][0][1] = MFMA16(a0, wz0, gi[0][0][1]);
      gi[0][0][2] = MFMA16(a0, wn0, gi[0][0][2]);
      gi[0][1][0] = MFMA16(a0, wr1, gi[0][1][0]);
      gi[0][1][1] = MFMA16(a0, wz1, gi[0][1][1]);
      gi[0][1][2] = MFMA16(a0, wn1, gi[0][1][2]);
      gi[1][0][0] = MFMA16(a1, wr0, gi[1][0][0]);
      gi[1][0][1] = MFMA16(a1, wz0, gi[1][0][1]);
      gi[1][0][2] = MFMA16(a1, wn0, gi[1][0][2]);
      gi[1][1][0] = MFMA16(a1, wr1, gi[1][1][0]);
      gi[1][1][1] = MFMA16(a1, wz1, gi[1][1][1]);
      gi[1][1][2] = MFMA16(a1, wn1, gi[1][1][2]);
      __builtin_amdgcn_s_setprio(0);
    }
    // no barrier: gi is thread-private; xfrag buffers not written until
    // step 2c+1, which is after barrier B(2c) -> all waves done reading.

    // ---------- two sequential steps (h-recurrence, fwh only) ----------
    #pragma unroll
    for (int s = 0; s < 2; ++s){
      const int k   = 2*c + s;
      const int cb  = s;          // k&1 == s (chunk-aligned)
      const int nbf = s ^ 1;

      // acc: [g][0]=r (init gi), [1]=z (init gi), [2]=h_n (init 0)
      f32x4 acc[2][3];
      #pragma unroll
      for (int g = 0; g < 2; ++g){
        acc[g][0] = gi[s][g][0];
        acc[g][1] = gi[s][g][1];
        f32x4 z4 = {0.f, 0.f, 0.f, 0.f};
        acc[g][2] = z4;
      }

      // during step 2c+1: issue next chunk's x loads (both steps) up-front
      float4 xa0, xa1, xb0, xb1;
      if (s == 1 && c < KK/2-1){
        const float4* pA = (const float4*)(item + ((size_t)(nb + xrow)*KK + (2*c+2))*DD + xo*8);
        const float4* pB = (const float4*)(item + ((size_t)(nb + xrow)*KK + (2*c+3))*DD + xo*8);
        xa0 = pA[0]; xa1 = pA[1]; xb0 = pB[0]; xb1 = pB[1];
      }

      // unroll 2 (not 4): 6 loads/tk x2 = 12 in flight, same as r12's 3x4
      #pragma unroll 2
      for (int tk = 0; tk < 8; ++tk){
        const int tkv = (tk + sk) & 7;
        const int o_  = tkv * 64;
        short8 hr0 = fwh[wq0+o_],      hz0 = fwh[wq1+o_],      hn0 = fwh[wq2+o_];
        short8 hr1 = fwh[wq0+4096+o_], hz1 = fwh[wq1+4096+o_], hn1 = fwh[wq2+4096+o_];
        short8 ah = *(const short8*)&hfrag[cb][((tkv)*64 + lane)*8];
        __builtin_amdgcn_s_setprio(1);
        acc[0][0] = MFMA16(ah, hr0, acc[0][0]);
        acc[0][1] = MFMA16(ah, hz0, acc[0][1]);
        acc[0][2] = MFMA16(ah, hn0, acc[0][2]);
        acc[1][0] = MFMA16(ah, hr1, acc[1][0]);
        acc[1][1] = MFMA16(ah, hz1, acc[1][1]);
        acc[1][2] = MFMA16(ah, hn1, acc[1][2]);
        __builtin_amdgcn_s_setprio(0);
      }

      // gates — in-register (v_rcp + v_med3; verified same absmax)
      float ypl[2][4];
      #pragma unroll
      for (int g = 0; g < 2; ++g)
        #pragma unroll
        for (int reg = 0; reg < 4; ++reg){
          float rp = acc[g][0][reg] + br_g[g];
          float zp = acc[g][1][reg] + bz_g[g];
          float r  = __builtin_amdgcn_rcpf(1.f + __expf(-rp));
          float z  = __builtin_amdgcn_rcpf(1.f + __expf(-zp));
          float np = gi[s][g][2][reg] + bin_g[g] + r*(acc[g][2][reg] + bhn_g[g]);
          np = __builtin_amdgcn_fmed3f(np, -30.f, 30.f);
          float e  = __expf(2.f*np);
          float n  = 1.f - 2.f*__builtin_amdgcn_rcpf(e + 1.f);   // tanh(np)
          float hv = (1.f - z)*n + z*h[g][reg];
          h[g][reg] = hv;
          ypl[g][reg] = hv * wo_g[g];
        }

      // y partial: reduce across the 16 cols of each owned group
      #pragma unroll
      for (int g = 0; g < 2; ++g)
        #pragma unroll
        for (int reg = 0; reg < 4; ++reg){
          float p = ypl[g][reg];
          p += __shfl_xor(p, 1);
          p += __shfl_xor(p, 2);
          p += __shfl_xor(p, 4);
          p += __shfl_xor(p, 8);
          if (col == 0) yp[k % 3][w + 8*g][q][reg] = p;
        }

      // write h' (bf16) into hfrag[nbf] for next step
      #pragma unroll
      for (int g = 0; g < 2; ++g)
        #pragma unroll
        for (int reg = 0; reg < 4; ++reg)
          hfrag[nbf][((tkk + 4*g)*64 + slb + q*4 + reg)*8 + dj] = f2bf(h[g][reg]);

      // stage next chunk's x into xfrag[0..1] (safe: past barrier B(2c))
      if (s == 1 && c < KK/2-1){
        uint4v t;
        t.x = cvtpk(xa0.x, xa0.y); t.y = cvtpk(xa0.z, xa0.w);
        t.z = cvtpk(xa1.x, xa1.y); t.w = cvtpk(xa1.z, xa1.w);
        *(uint4v*)&xfrag[0][((xtk)*64 + xsl)*8] = t;
        t.x = cvtpk(xb0.x, xb0.y); t.y = cvtpk(xb0.z, xb0.w);
        t.z = cvtpk(xb1.x, xb1.y); t.w = cvtpk(xb1.z, xb1.w);
        *(uint4v*)&xfrag[1][((xtk)*64 + xsl)*8] = t;
      }

      // finalize y for step k-1 (yp[(k-1)%3] stable since previous barrier)
      if (k > 0 && tid < 16){
        float sacc = bout;
        #pragma unroll
        for (int ww = 0; ww < 16; ++ww)
          sacc += yp[(k-1) % 3][ww][tid >> 2][tid & 3];
        out[(size_t)(nb + tid)*KK + (k-1)] = sacc;
      }

      // raw barrier: order LDS only; do NOT drain vmcnt (out-store + x loads
      // may stay in flight; disjoint addresses, kernel-end release suffices)
      asm volatile("s_waitcnt lgkmcnt(0)" ::: "memory");
      __builtin_amdgcn_s_barrier();
      __builtin_amdgcn_sched_barrier(0);
    }
  }

  // finalize y for the last step
  if (tid < 16){
    float s = bout;
    #pragma unroll
    for (int ww = 0; ww < 16; ++ww)
      s += yp[(KK-1) % 3][ww][tid >> 2][tid & 3];
    out[(size_t)(nb + tid)*KK + (KK-1)] = s;
  }
}

extern "C" void kernel_launch(void* const* d_in, const int* in_sizes, int n_in,
                              void* d_out, int out_size, void* d_ws, size_t ws_size,
                              hipStream_t stream) {
  const float* item   = (const float*)d_in[0];
  const float* user   = (const float*)d_in[1];
  const float* W_ih   = (const float*)d_in[2];
  const float* W_hh   = (const float*)d_in[3];
  const float* b_ih   = (const float*)d_in[4];
  const float* b_hh   = (const float*)d_in[5];
  const float* w_out  = (const float*)d_in[6];
  const float* b_out  = (const float*)d_in[7];
  const int*   length = (const int*)d_in[8];
  unsigned short* ws  = (unsigned short*)d_ws;   // needs 768 KB
  float* out = (float*)d_out;

  hipLaunchKernelGGL(prep_weights, dim3((2*FRAG_ROWS)/256), dim3(256), 0, stream,
                     W_ih, W_hh, ws);
  hipLaunchKernelGGL(gru_main, dim3(NBLK), dim3(NT), 0, stream,
                     item, user, b_ih, b_hh, w_out, b_out, length, ws, out);
}

// Round 15
// 217.362 us; speedup vs baseline: 1.1808x; 1.1808x over previous
//
#include <hip/hip_runtime.h>

#define BB 128
#define SS 64
#define KK 10
#define DD 256
#define NN (BB*SS)        // 8192 rows
#define ROWS 32           // rows per block
#define NBLK (NN/ROWS)    // 256 blocks = 1 per CU
#define NT 1024           // 16 waves per block -> 4 waves/SIMD

typedef __attribute__((ext_vector_type(8))) short short8;
typedef __attribute__((ext_vector_type(4))) float f32x4;
typedef __attribute__((ext_vector_type(4))) unsigned uint4v;

#define FRAG_ELEMS (48*8*64*8)   // 196608 bf16 values per weight matrix
#define FRAG_ROWS  (48*8*64)     // 24576 8-element fragment rows per matrix

__device__ __forceinline__ unsigned short f2bf(float f){
  union { float f; unsigned u; } v; v.f = f;
  unsigned r = (v.u + 0x7FFFu + ((v.u >> 16) & 1u)) >> 16;
  return (unsigned short)r;
}

// packed RNE f32->bf16 pair (no builtin on gfx950); same rounding as f2bf.
__device__ __forceinline__ unsigned cvtpk(float lo, float hi){
  unsigned r;
  asm("v_cvt_pk_bf16_f32 %0, %1, %2" : "=v"(r) : "v"(lo), "v"(hi));
  return r;
}

// Pre-swizzle W_ih[:, :D] and W_hh into bf16 MFMA B-fragment order:
// frag value at (tn, tk, lane, j) = W[c = tn*16 + (lane&15)][d = tk*32 + (lane>>4)*8 + j]
// stored flat at ((tn*8+tk)*64 + lane)*8 + j.  FW1 first, FWhh second.
// Vectorized: one thread per fragment row (8 contiguous W elems -> short8).
__global__ void prep_weights(const float* __restrict__ Wih,
                             const float* __restrict__ Whh,
                             unsigned short* __restrict__ fw){
  int t = blockIdx.x * 256 + threadIdx.x;      // 0 .. 2*FRAG_ROWS-1
  int arr = (t >= FRAG_ROWS);
  int r = arr ? (t - FRAG_ROWS) : t;
  int l  = r & 63;
  int tk = (r >> 6) & 7;
  int tn = r >> 9;                             // 0..47
  int c  = tn * 16 + (l & 15);                 // 0..767
  int d0 = tk * 32 + ((l >> 4) << 3);          // 0..255, 8-aligned
  const float* src = arr ? (Whh + (size_t)c*256 + d0) : (Wih + (size_t)c*512 + d0);
  const float4* p = (const float4*)src;
  float4 a0 = p[0], a1 = p[1];
  unsigned short o[8];
  o[0]=f2bf(a0.x); o[1]=f2bf(a0.y); o[2]=f2bf(a0.z); o[3]=f2bf(a0.w);
  o[4]=f2bf(a1.x); o[5]=f2bf(a1.y); o[6]=f2bf(a1.z); o[7]=f2bf(a1.w);
  *(short8*)&fw[(size_t)t*8] = *(short8*)o;
}

// FINAL KERNEL (r9/r12 structure, proven 3x at 115-117us):
// 256 blocks x 1024 thr, 4 waves/SIMD. Per chunk of 2 steps: GI GEMM
// (x-part of gates, fw1 read once, barrier-free, thread-private C-layout
// accumulators) + 2 sequential h-steps reading only fwh (halved dependent
// load chain), acc init = gi.
// SESSION CONSTRAINTS (all measured):
// - arch-VGPR cap is 64 at this geometry; 5 spill events prove zero headroom
//   (rings r2/r3, prime r7, literal-offset scheduling r11, 2-blk/CU r14).
// - tk-skew + sched_barrier(0) are liveness governors (r11: removing ->
//   WRITE 3->115MB scratch). Keep them.
// - occupancy trades lose (r4/r5/r14); 4 waves/SIMD + 1 blk/CU is optimal.
// - plateau is latency-serialization (L2 stream + MFMA + gates serialized by
//   the h-recurrence barrier), not a HW roofline: MfmaUtil 23%, HBM 5%.
__global__ __launch_bounds__(NT, 4) void gru_main(
    const float* __restrict__ item, const float* __restrict__ user,
    const float* __restrict__ b_ih, const float* __restrict__ b_hh,
    const float* __restrict__ w_out, const float* __restrict__ b_out,
    const int* __restrict__ length, const unsigned short* __restrict__ ws,
    float* __restrict__ out)
{
  // A-fragment layout: elem (mt, tk, lane, j) at ((mt*8+tk)*64+lane)*8+j
  // xfrag[s] holds x for step 2c+s of the current chunk.
  __shared__ unsigned short xfrag[2][2*8*64*8];   // 32 KB
  __shared__ unsigned short hfrag[2][2*8*64*8];   // 32 KB
  __shared__ float yp[3][16][2][4][4];            // 6 KB, triple-buffered

  const int tid  = threadIdx.x;
  const int lane = tid & 63;
  const int w    = tid >> 6;        // wave 0..15 == column group g
  const int col  = lane & 15;       // C-layout col
  const int q    = lane >> 4;       // quad
  const int nb   = blockIdx.x * ROWS;
  const int b    = nb / SS;         // one user per block (32 | 64)
  const int sk   = blockIdx.x & 7;  // tk read-order skew + liveness governor

  const short8* fw1 = (const short8*)ws;
  const short8* fwh = fw1 + (FRAG_ELEMS/8);

  // per-column constants (this thread owns output channel d for 8 rows)
  const int d    = w*16 + col;
  const float br_  = b_ih[d]       + b_hh[d];
  const float bz_  = b_ih[256 + d] + b_hh[256 + d];
  const float bin_ = b_ih[512 + d];
  const float bhn_ = b_hh[512 + d];
  const float wo_  = w_out[d];

  // weight fragment flat offsets (short8 units): frag(tn,tk) = fw[tn*512 + tk*64 + lane]
  const int wq0 = (w     )*512 + lane;   // gate r
  const int wq1 = (16 + w)*512 + lane;   // gate z
  const int wq2 = (32 + w)*512 + lane;   // gate n

  // h0 = user_embs[b, clip(length[b]-1,0)]; identical for all 32 rows
  int idx = length[b] - 1; if (idx < 0) idx = 0;
  const float u0 = user[((size_t)b*SS + idx)*DD + d];
  float h[2][4];
  #pragma unroll
  for (int mt = 0; mt < 2; ++mt)
    #pragma unroll
    for (int reg = 0; reg < 4; ++reg)
      h[mt][reg] = u0;

  // write h0 into hfrag[0] (A-fragment layout), owner-thread scatter
  const int tkk = d >> 5;
  const int slb = ((d >> 3) & 3) * 16;
  const int dj  = d & 7;
  {
    unsigned short hb = f2bf(u0);
    #pragma unroll
    for (int mt = 0; mt < 2; ++mt)
      #pragma unroll
      for (int reg = 0; reg < 4; ++reg)
        hfrag[0][((mt*8 + tkk)*64 + slb + q*4 + reg)*8 + dj] = hb;
  }

  // cooperative x staging for steps 0 and 1
  const int xrow = tid >> 5;        // 0..31
  const int xo   = tid & 31;        // which 8-wide d chunk
  const int xmt  = xrow >> 4;
  const int xtk  = xo >> 2;
  const int xsl  = (xo & 3)*16 + (xrow & 15);
  #pragma unroll
  for (int s = 0; s < 2; ++s){
    const float4* p = (const float4*)(item + ((size_t)(nb + xrow)*KK + s)*DD + xo*8);
    float4 a0 = p[0], a1 = p[1];
    uint4v t;
    t.x = cvtpk(a0.x, a0.y); t.y = cvtpk(a0.z, a0.w);
    t.z = cvtpk(a1.x, a1.y); t.w = cvtpk(a1.z, a1.w);
    *(uint4v*)&xfrag[s][((xmt*8 + xtk)*64 + xsl)*8] = t;
  }
  __syncthreads();

  const float bout = b_out[0];

#define MFMA16(A,Bv,C) __builtin_amdgcn_mfma_f32_16x16x32_bf16(A,Bv,C,0,0,0)

  for (int c = 0; c < KK/2; ++c){
    // ---------- GI GEMM: x-part of gates for steps 2c and 2c+1 ----------
    f32x4 gi[2][2][3];   // [step][mt][r,z,n]
    #pragma unroll
    for (int s = 0; s < 2; ++s)
      #pragma unroll
      for (int mt = 0; mt < 2; ++mt)
        #pragma unroll
        for (int g = 0; g < 3; ++g){
          f32x4 z4 = {0.f, 0.f, 0.f, 0.f};
          gi[s][mt][g] = z4;
        }

    #pragma unroll 2
    for (int tk = 0; tk < 8; ++tk){
      const int tkv = (tk + sk) & 7;
      const int o_  = tkv * 64;
      short8 w1r = fw1[wq0+o_], w1z = fw1[wq1+o_], w1n = fw1[wq2+o_];
      short8 a00 = *(const short8*)&xfrag[0][((    tkv)*64 + lane)*8];
      short8 a01 = *(const short8*)&xfrag[0][((8 + tkv)*64 + lane)*8];
      short8 a10 = *(const short8*)&xfrag[1][((    tkv)*64 + lane)*8];
      short8 a11 = *(const short8*)&xfrag[1][((8 + tkv)*64 + lane)*8];
      __builtin_amdgcn_s_setprio(1);
      gi[0][0][0] = MFMA16(a00, w1r, gi[0][0][0]);
      gi[0][0][1] = MFMA16(a00, w1z, gi[0][0][1]);
      gi[0][0][2] = MFMA16(a00, w1n, gi[0][0][2]);
      gi[0][1][0] = MFMA16(a01, w1r, gi[0][1][0]);
      gi[0][1][1] = MFMA16(a01, w1z, gi[0][1][1]);
      gi[0][1][2] = MFMA16(a01, w1n, gi[0][1][2]);
      gi[1][0][0] = MFMA16(a10, w1r, gi[1][0][0]);
      gi[1][0][1] = MFMA16(a10, w1z, gi[1][0][1]);
      gi[1][0][2] = MFMA16(a10, w1n, gi[1][0][2]);
      gi[1][1][0] = MFMA16(a11, w1r, gi[1][1][0]);
      gi[1][1][1] = MFMA16(a11, w1z, gi[1][1][1]);
      gi[1][1][2] = MFMA16(a11, w1n, gi[1][1][2]);
      __builtin_amdgcn_s_setprio(0);
    }
    // no barrier: gi is thread-private; xfrag buffers not written until
    // step 2c+1, which is after barrier B(2c) -> all waves done reading.

    // ---------- two sequential steps (h-recurrence, fwh only) ----------
    #pragma unroll
    for (int s = 0; s < 2; ++s){
      const int k   = 2*c + s;
      const int cb  = s;          // k&1 == s (chunk-aligned)
      const int nbf = s ^ 1;

      // acc: [mt][0]=r (init gi), [1]=z (init gi), [2]=h_n (init 0)
      f32x4 acc[2][3];
      #pragma unroll
      for (int mt = 0; mt < 2; ++mt){
        acc[mt][0] = gi[s][mt][0];
        acc[mt][1] = gi[s][mt][1];
        f32x4 z4 = {0.f, 0.f, 0.f, 0.f};
        acc[mt][2] = z4;
      }

      // during step 2c+1: issue next chunk's x loads (both steps) up-front
      float4 xa0, xa1, xb0, xb1;
      if (s == 1 && c < KK/2-1){
        const float4* pA = (const float4*)(item + ((size_t)(nb + xrow)*KK + (2*c+2))*DD + xo*8);
        const float4* pB = (const float4*)(item + ((size_t)(nb + xrow)*KK + (2*c+3))*DD + xo*8);
        xa0 = pA[0]; xa1 = pA[1]; xb0 = pB[0]; xb1 = pB[1];
      }

      #pragma unroll 4
      for (int tk = 0; tk < 8; ++tk){
        const int tkv = (tk + sk) & 7;
        const int o_  = tkv * 64;
        short8 whr = fwh[wq0+o_], whz = fwh[wq1+o_], whn = fwh[wq2+o_];
        short8 ah0 = *(const short8*)&hfrag[cb][((    tkv)*64 + lane)*8];
        short8 ah1 = *(const short8*)&hfrag[cb][((8 + tkv)*64 + lane)*8];
        __builtin_amdgcn_s_setprio(1);
        acc[0][0] = MFMA16(ah0, whr, acc[0][0]);
        acc[0][1] = MFMA16(ah0, whz, acc[0][1]);
        acc[0][2] = MFMA16(ah0, whn, acc[0][2]);
        acc[1][0] = MFMA16(ah1, whr, acc[1][0]);
        acc[1][1] = MFMA16(ah1, whz, acc[1][1]);
        acc[1][2] = MFMA16(ah1, whn, acc[1][2]);
        __builtin_amdgcn_s_setprio(0);
      }

      // gates — in-register (v_rcp + v_med3; verified same absmax)
      float ypl[2][4];
      #pragma unroll
      for (int mt = 0; mt < 2; ++mt)
        #pragma unroll
        for (int reg = 0; reg < 4; ++reg){
          float rp = acc[mt][0][reg] + br_;
          float zp = acc[mt][1][reg] + bz_;
          float r  = __builtin_amdgcn_rcpf(1.f + __expf(-rp));
          float z  = __builtin_amdgcn_rcpf(1.f + __expf(-zp));
          float np = gi[s][mt][2][reg] + bin_ + r*(acc[mt][2][reg] + bhn_);
          np = __builtin_amdgcn_fmed3f(np, -30.f, 30.f);
          float e  = __expf(2.f*np);
          float n  = 1.f - 2.f*__builtin_amdgcn_rcpf(e + 1.f);   // tanh(np)
          float hv = (1.f - z)*n + z*h[mt][reg];
          h[mt][reg] = hv;
          ypl[mt][reg] = hv * wo_;
        }

      // y partial: reduce across the 16 cols of this wave's group
      #pragma unroll
      for (int mt = 0; mt < 2; ++mt)
        #pragma unroll
        for (int reg = 0; reg < 4; ++reg){
          float p = ypl[mt][reg];
          p += __shfl_xor(p, 1);
          p += __shfl_xor(p, 2);
          p += __shfl_xor(p, 4);
          p += __shfl_xor(p, 8);
          if (col == 0) yp[k % 3][w][mt][q][reg] = p;
        }

      // write h' (bf16) into hfrag[nbf] for next step
      #pragma unroll
      for (int mt = 0; mt < 2; ++mt)
        #pragma unroll
        for (int reg = 0; reg < 4; ++reg)
          hfrag[nbf][((mt*8 + tkk)*64 + slb + q*4 + reg)*8 + dj] = f2bf(h[mt][reg]);

      // stage next chunk's x into xfrag[0..1] (safe: past barrier B(2c),
      // so every wave has finished this chunk's GI GEMM reads)
      if (s == 1 && c < KK/2-1){
        uint4v t;
        t.x = cvtpk(xa0.x, xa0.y); t.y = cvtpk(xa0.z, xa0.w);
        t.z = cvtpk(xa1.x, xa1.y); t.w = cvtpk(xa1.z, xa1.w);
        *(uint4v*)&xfrag[0][((xmt*8 + xtk)*64 + xsl)*8] = t;
        t.x = cvtpk(xb0.x, xb0.y); t.y = cvtpk(xb0.z, xb0.w);
        t.z = cvtpk(xb1.x, xb1.y); t.w = cvtpk(xb1.z, xb1.w);
        *(uint4v*)&xfrag[1][((xmt*8 + xtk)*64 + xsl)*8] = t;
      }

      // finalize y for step k-1 (yp[(k-1)%3] stable since previous barrier)
      if (k > 0 && tid < 32){
        float sacc = bout;
        #pragma unroll
        for (int ww = 0; ww < 16; ++ww)
          sacc += yp[(k-1) % 3][ww][tid >> 4][(tid >> 2) & 3][tid & 3];
        out[(size_t)(nb + tid)*KK + (k-1)] = sacc;
      }

      // raw barrier: order LDS only; do NOT drain vmcnt (out-store + x loads
      // may stay in flight; disjoint addresses, kernel-end release suffices)
      asm volatile("s_waitcnt lgkmcnt(0)" ::: "memory");
      __builtin_amdgcn_s_barrier();
      __builtin_amdgcn_sched_barrier(0);
    }
  }

  // finalize y for the last step
  if (tid < 32){
    float s = bout;
    #pragma unroll
    for (int ww = 0; ww < 16; ++ww)
      s += yp[(KK-1) % 3][ww][tid >> 4][(tid >> 2) & 3][tid & 3];
    out[(size_t)(nb + tid)*KK + (KK-1)] = s;
  }
}

extern "C" void kernel_launch(void* const* d_in, const int* in_sizes, int n_in,
                              void* d_out, int out_size, void* d_ws, size_t ws_size,
                              hipStream_t stream) {
  const float* item   = (const float*)d_in[0];
  const float* user   = (const float*)d_in[1];
  const float* W_ih   = (const float*)d_in[2];
  const float* W_hh   = (const float*)d_in[3];
  const float* b_ih   = (const float*)d_in[4];
  const float* b_hh   = (const float*)d_in[5];
  const float* w_out  = (const float*)d_in[6];
  const float* b_out  = (const float*)d_in[7];
  const int*   length = (const int*)d_in[8];
  unsigned short* ws  = (unsigned short*)d_ws;   // needs 768 KB
  float* out = (float*)d_out;

  hipLaunchKernelGGL(prep_weights, dim3((2*FRAG_ROWS)/256), dim3(256), 0, stream,
                     W_ih, W_hh, ws);
  hipLaunchKernelGGL(gru_main, dim3(NBLK), dim3(NT), 0, stream,
                     item, user, b_ih, b_hh, w_out, b_out, length, ws, out);
}